// Round 2
// baseline (577.024 us; speedup 1.0000x reference)
//
#include <hip/hip_runtime.h>
#include <stdint.h>

// Problem constants (from reference): B=4, S=2048, D_IN=D_OUT=4096
constexpr int M = 4 * 2048;   // 8192 tokens
constexpr int K = 4096;       // D_IN
constexpr int N = 4096;       // D_OUT
constexpr float EPSf = 1e-5f;
constexpr float QMAX = 127.0f;

typedef __attribute__((ext_vector_type(8))) short bf16x8;   // 8 bf16 (4 VGPRs)
typedef __attribute__((ext_vector_type(4))) float f32x4;    // MFMA C/D

// bf16 round-to-nearest-even from f32 (no NaN inputs here)
__device__ __forceinline__ unsigned short f2bf(float f) {
  union { float f; uint32_t u; } c; c.f = f;
  uint32_t u = c.u;
  return (unsigned short)((u + 0x7fffu + ((u >> 16) & 1u)) >> 16);
}

__device__ __forceinline__ void async_copy16(const void* g, const void* l) {
  __builtin_amdgcn_global_load_lds(
      (const __attribute__((address_space(1))) unsigned int*)g,
      (__attribute__((address_space(3))) unsigned int*)l, 16, 0, 0);
}

// ---------------- Kernel 1: per-token, per-group(64) absmax fake-quant -> bf16
__global__ void __launch_bounds__(256) quant_x_kernel(const float* __restrict__ x,
                                                      unsigned short* __restrict__ xq) {
  const int t = blockIdx.x * 256 + threadIdx.x;     // float4 index
  const float4 v = ((const float4*)x)[t];
  float m = fmaxf(fmaxf(fabsf(v.x), fabsf(v.y)), fmaxf(fabsf(v.z), fabsf(v.w)));
  #pragma unroll
  for (int d = 1; d < 16; d <<= 1) m = fmaxf(m, __shfl_xor(m, d));
  m = fmaxf(m, EPSf);
  const float scale = QMAX / m;

  float q0 = fminf(fmaxf(rintf(v.x * scale), -QMAX), QMAX);
  float q1 = fminf(fmaxf(rintf(v.y * scale), -QMAX), QMAX);
  float q2 = fminf(fmaxf(rintf(v.z * scale), -QMAX), QMAX);
  float q3 = fminf(fmaxf(rintf(v.w * scale), -QMAX), QMAX);
  ushort4 o;
  o.x = f2bf(q0 / scale);
  o.y = f2bf(q1 / scale);
  o.z = f2bf(q2 / scale);
  o.w = f2bf(q3 / scale);
  ((ushort4*)xq)[t] = o;
}

// ---------------- Kernel 2: per-row ternary absmean quant of W
__global__ void __launch_bounds__(256) quant_w_kernel(const float* __restrict__ w,
                                                      unsigned short* __restrict__ wt,
                                                      float* __restrict__ wscale) {
  const int row = blockIdx.x;
  const int tid = threadIdx.x;
  const float* wr = w + (long)row * K;
  float4 v[4];
  float s = 0.f;
  #pragma unroll
  for (int p = 0; p < 4; p++) {
    v[p] = ((const float4*)wr)[tid + p * 256];
    s += fabsf(v[p].x) + fabsf(v[p].y) + fabsf(v[p].z) + fabsf(v[p].w);
  }
  #pragma unroll
  for (int d = 1; d < 64; d <<= 1) s += __shfl_xor(s, d);
  __shared__ float red[4];
  if ((tid & 63) == 0) red[tid >> 6] = s;
  __syncthreads();
  const float tot = red[0] + red[1] + red[2] + red[3];
  const float sc = fmaxf(tot / (float)K, EPSf);
  if (tid == 0) wscale[row] = sc;
  unsigned short* wrow = wt + (long)row * K;
  #pragma unroll
  for (int p = 0; p < 4; p++) {
    ushort4 o;
    o.x = f2bf(fminf(fmaxf(rintf(v[p].x / sc), -1.f), 1.f));
    o.y = f2bf(fminf(fmaxf(rintf(v[p].y / sc), -1.f), 1.f));
    o.z = f2bf(fminf(fmaxf(rintf(v[p].z / sc), -1.f), 1.f));
    o.w = f2bf(fminf(fmaxf(rintf(v[p].w / sc), -1.f), 1.f));
    ((ushort4*)wrow)[tid + p * 256] = o;
  }
}

// ---------------- Kernel 3: 256x256-tile 8-phase GEMM, 1-phase-ahead reg prefetch
// C[M,N] = A[M,K] * Bt[N,K]^T, epilogue * wscale[n].
// 8 waves (2M x 4N), per-wave 128x64 output, BK=64, LDS 128 KiB dbuf.
// vs r1: ds_reads for phase p's MFMA are issued in phase p-1 (hidden under
// that phase's MFMA block); exactly one half-tile staged per phase; counted
// vmcnt(6) moved to ph3/ph7; no explicit lgkmcnt (compiler emits partial
// in-order DS waits); precomputed per-thread offsets; peeled tail iteration.
//
// Steady-state invariant: 8 gload_lds in flight at iteration entry
// (= next tile's 4 half-tiles). vmcnt(6) at ph3 drains buf^1's tile; at ph7
// drains buf's next tile (verified by in-flight accounting, 2/phase).

#define BAR() do { asm volatile("" ::: "memory"); \
                   __builtin_amdgcn_s_barrier();  \
                   asm volatile("" ::: "memory"); } while (0)
#define VMCNT(n) asm volatile("s_waitcnt vmcnt(" #n ")" ::: "memory")

__global__ void __launch_bounds__(512, 2) gemm_bt_kernel(const short* __restrict__ A,
                                                         const short* __restrict__ Bt,
                                                         const float* __restrict__ wscale,
                                                         float* __restrict__ C) {
  __shared__ short smem[65536];   // 128 KiB: 2 buffers x (A 16K shorts | B 16K shorts)

  const int tid  = (int)threadIdx.x;
  const int lane = tid & 63;
  const int wv   = tid >> 6;
  const int wm = wv & 1, wn = wv >> 1;        // 2 M-waves x 4 N-waves
  const int quad = lane >> 4, r16 = lane & 15;

  // T1: XCD-aware bijective swizzle (nwg=512, 512 % 8 == 0)
  const int f = (int)blockIdx.x;
  const int s = (f & 7) * 64 + (f >> 3);
  const int m0 = (s >> 4) * 256;              // 32 M-tiles
  const int n0 = (s & 15) * 256;              // 16 N-tiles

  const short* Ab = A  + (long)m0 * K;
  const short* Bb = Bt + (long)n0 * K;

  // Staging: thread t, call c stages phys chunk (t&7) of phys row c*64+(t>>3);
  // logical k-chunk = (t&7) ^ ((t>>3)&7)  (inverse swizzle).
  const int s_row8 = tid >> 3;                              // 0..63
  const int s_kc   = ((tid & 7) ^ (s_row8 & 7)) * 8;        // k elem offset (shorts)
  const int athr = s_row8 * K + s_kc;                       // per-thread A stage off
  const int bthr = ((tid >> 8) * 64 + (s_row8 & 31)) * K + s_kc;  // per-thread B

  // ds_read: logical chunk kh*4+quad, phys = ^(r16&7); shorts offsets
  const int ksw0 = (((quad * 16)      ) ^ ((r16 & 7) << 4)) >> 1;  // kh=0
  const int ksw1 = (((quad * 16) + 64 ) ^ ((r16 & 7) << 4)) >> 1;  // kh=1
  const int aro  = (wm * 64 + r16) * 64;      // A slot row offset (shorts)
  const int bro  = (wn * 32 + r16) * 64;      // B slot row offset (shorts)

  f32x4 acc[8][4];
  #pragma unroll
  for (int i = 0; i < 8; i++)
    #pragma unroll
    for (int j = 0; j < 4; j++) acc[i][j] = (f32x4){0.f, 0.f, 0.f, 0.f};

  bf16x8 afX[4][2], afY[4][2];    // A frag double-buffer (mi0 -> X, mi1 -> Y)
  bf16x8 bS0[2][2], bS1[2][2];    // B frag slots (rotate per tile)

#define STAGE_A(buf, hh, kt) do {                                              \
    short* _d = smem + (buf) * 32768 + (hh) * 8192 + tid * 8;                  \
    const short* _g = Ab + ((hh) * 64 * K + (kt) * 64) + athr;                 \
    async_copy16(_g, _d);                                                      \
    async_copy16(_g + 128 * K, _d + 4096);                                     \
  } while (0)

#define STAGE_B(buf, hh, kt) do {                                              \
    short* _d = smem + (buf) * 32768 + 16384 + (hh) * 8192 + tid * 8;          \
    const short* _g = Bb + ((hh) * 32 * K + (kt) * 64) + bthr;                 \
    async_copy16(_g, _d);                                                      \
    async_copy16(_g + 128 * K, _d + 4096);                                     \
  } while (0)

#define LOAD_A(DST, buf, mi) do {                                              \
    const short* _b = smem + (buf) * 32768 + (mi) * 8192 + aro;                \
    _Pragma("unroll") for (int _mt = 0; _mt < 4; ++_mt) {                      \
      DST[_mt][0] = *(const bf16x8*)(_b + _mt * 1024 + ksw0);                  \
      DST[_mt][1] = *(const bf16x8*)(_b + _mt * 1024 + ksw1);                  \
    }                                                                          \
  } while (0)

#define LOAD_B(DST, buf, nj) do {                                              \
    const short* _b = smem + (buf) * 32768 + 16384 + (nj) * 8192 + bro;        \
    _Pragma("unroll") for (int _nt = 0; _nt < 2; ++_nt) {                      \
      DST[_nt][0] = *(const bf16x8*)(_b + _nt * 1024 + ksw0);                  \
      DST[_nt][1] = *(const bf16x8*)(_b + _nt * 1024 + ksw1);                  \
    }                                                                          \
  } while (0)

  // 16 MFMAs: acc[MB+mt][NB+nt] += AF[mt][kh] * BF[nt][kh]. Operands were
  // ds_read one phase earlier; compiler's auto partial lgkm waits cover them.
#define MFMA_Q(AF, BF, MB, NB) do {                                            \
    __builtin_amdgcn_s_setprio(1);                                             \
    _Pragma("unroll") for (int _mt = 0; _mt < 4; ++_mt)                        \
    _Pragma("unroll") for (int _nt = 0; _nt < 2; ++_nt) {                      \
      acc[(MB)+_mt][(NB)+_nt] = __builtin_amdgcn_mfma_f32_16x16x32_bf16(       \
          AF[_mt][0], BF[_nt][0], acc[(MB)+_mt][(NB)+_nt], 0, 0, 0);           \
      acc[(MB)+_mt][(NB)+_nt] = __builtin_amdgcn_mfma_f32_16x16x32_bf16(       \
          AF[_mt][1], BF[_nt][1], acc[(MB)+_mt][(NB)+_nt], 0, 0, 0);           \
    }                                                                          \
    __builtin_amdgcn_s_setprio(0);                                             \
  } while (0)

  // Prologue: tile0 -> buf0 (drained), tile1 -> buf1 (8 loads in flight),
  // prime ph1's fragments (afX = A-mi0(t0), bS0 = B-nj0(t0)).
  STAGE_A(0, 0, 0); STAGE_B(0, 0, 0); STAGE_B(0, 1, 0); STAGE_A(0, 1, 0);
  VMCNT(0); BAR();
  STAGE_A(1, 0, 1); STAGE_B(1, 0, 1); STAGE_B(1, 1, 1); STAGE_A(1, 1, 1);
  LOAD_A(afX, 0, 0); LOAD_B(bS0, 0, 0);
  BAR();

  for (int kt = 0; kt <= 60; kt += 2) {
    // ======== tile kt (buf0): nj0=bS0, nj1=bS1 ========
    // ph1: reads bf1(kt)->S1 for ph2; stage buf0-A0<-kt+2
    STAGE_A(0, 0, kt + 2); LOAD_B(bS1, 0, 1);
    BAR(); MFMA_Q(afX, bS0, 0, 0); BAR();
    // ph2: reads A-mi1(kt)->Y for ph3; stage buf0-B0<-kt+2
    STAGE_B(0, 0, kt + 2); LOAD_A(afY, 0, 1);
    BAR(); MFMA_Q(afX, bS1, 0, 2); BAR();
    // ph3: no reads (ph4 cached); stage buf0-B1<-kt+2; drain buf1 tile kt+1
    STAGE_B(0, 1, kt + 2);
    VMCNT(6);
    BAR(); MFMA_Q(afY, bS1, 4, 2); BAR();
    // ph4: reads A-mi0(kt+1)->X, bf0(kt+1)->S1 for ph5; stage buf0-A1<-kt+2
    STAGE_A(0, 1, kt + 2); LOAD_A(afX, 1, 0); LOAD_B(bS1, 1, 0);
    BAR(); MFMA_Q(afY, bS0, 4, 0); BAR();
    // ======== tile kt+1 (buf1): nj0=bS1, nj1=bS0 ========
    // ph5: reads bf1(kt+1)->S0 for ph6; stage buf1-A0<-kt+3
    STAGE_A(1, 0, kt + 3); LOAD_B(bS0, 1, 1);
    BAR(); MFMA_Q(afX, bS1, 0, 0); BAR();
    // ph6: reads A-mi1(kt+1)->Y for ph7; stage buf1-B0<-kt+3
    STAGE_B(1, 0, kt + 3); LOAD_A(afY, 1, 1);
    BAR(); MFMA_Q(afX, bS0, 0, 2); BAR();
    // ph7: no reads; stage buf1-B1<-kt+3; drain buf0 tile kt+2
    STAGE_B(1, 1, kt + 3);
    VMCNT(6);
    BAR(); MFMA_Q(afY, bS0, 4, 2); BAR();
    // ph8: reads A-mi0(kt+2)->X, bf0(kt+2)->S0 for next ph1; stage buf1-A1<-kt+3
    STAGE_A(1, 1, kt + 3); LOAD_A(afX, 0, 0); LOAD_B(bS0, 0, 0);
    BAR(); MFMA_Q(afY, bS1, 4, 0); BAR();
  }

  // ======== tail: tiles 62 (buf0) / 63 (buf1), no stages ========
  LOAD_B(bS1, 0, 1);
  BAR(); MFMA_Q(afX, bS0, 0, 0); BAR();
  LOAD_A(afY, 0, 1);
  BAR(); MFMA_Q(afX, bS1, 0, 2); BAR();
  VMCNT(0);                                   // drain tile 63 (8 loads)
  BAR(); MFMA_Q(afY, bS1, 4, 2); BAR();
  LOAD_A(afX, 1, 0); LOAD_B(bS1, 1, 0);
  BAR(); MFMA_Q(afY, bS0, 4, 0); BAR();
  LOAD_B(bS0, 1, 1);
  BAR(); MFMA_Q(afX, bS1, 0, 0); BAR();
  LOAD_A(afY, 1, 1);
  BAR(); MFMA_Q(afX, bS0, 0, 2); BAR();
  BAR(); MFMA_Q(afY, bS0, 4, 2); BAR();
  MFMA_Q(afY, bS1, 4, 0);

  // Epilogue: D[row = quad*4+r][col = r16] per 16x16 frag; scale by wscale[col]
  #pragma unroll
  for (int an = 0; an < 4; ++an) {
    const int col = n0 + wn * 64 + (an >> 1) * 32 + (an & 1) * 16 + r16;
    const float sc = wscale[col];
    #pragma unroll
    for (int am = 0; am < 8; ++am) {
      const int rb = m0 + wm * 128 + (am >> 2) * 64 + (am & 3) * 16 + quad * 4;
      #pragma unroll
      for (int r = 0; r < 4; ++r)
        C[(long)(rb + r) * N + col] = acc[am][an][r] * sc;
    }
  }
}

extern "C" void kernel_launch(void* const* d_in, const int* in_sizes, int n_in,
                              void* d_out, int out_size, void* d_ws, size_t ws_size,
                              hipStream_t stream) {
  const float* x   = (const float*)d_in[0];   // [4,2048,4096] fp32
  const float* wgt = (const float*)d_in[1];   // [4096,4096] fp32
  float* out = (float*)d_out;                 // [4,2048,4096] fp32

  // Workspace layout: A bf16 [M*K] | T bf16 [N*K] | wscale f32 [N]  (~96 MB)
  unsigned short* Aq = (unsigned short*)d_ws;
  unsigned short* Tq = Aq + (size_t)M * K;
  float* wscale = (float*)(Tq + (size_t)N * K);

  quant_x_kernel<<<(M * K / 4) / 256, 256, 0, stream>>>(x, Aq);
  quant_w_kernel<<<N, 256, 0, stream>>>(wgt, Tq, wscale);

  gemm_bt_kernel<<<dim3(512), dim3(512), 0, stream>>>((const short*)Aq, (const short*)Tq,
                                                      wscale, out);
}

// Round 3
// 477.067 us; speedup vs baseline: 1.2095x; 1.2095x over previous
//
#include <hip/hip_runtime.h>
#include <stdint.h>

// Problem constants (from reference): B=4, S=2048, D_IN=D_OUT=4096
constexpr int M = 4 * 2048;   // 8192 tokens
constexpr int K = 4096;       // D_IN
constexpr int N = 4096;       // D_OUT
constexpr float EPSf = 1e-5f;
constexpr float QMAX = 127.0f;

typedef __attribute__((ext_vector_type(8))) short bf16x8;   // 8 bf16 (4 VGPRs)
typedef __attribute__((ext_vector_type(4))) float f32x4;    // MFMA C/D
typedef __attribute__((ext_vector_type(8))) unsigned short ushort8;

// bf16 round-to-nearest-even from f32 (no NaN inputs here)
__device__ __forceinline__ unsigned short f2bf(float f) {
  union { float f; uint32_t u; } c; c.f = f;
  uint32_t u = c.u;
  return (unsigned short)((u + 0x7fffu + ((u >> 16) & 1u)) >> 16);
}

__device__ __forceinline__ void async_copy16(const void* g, const void* l) {
  __builtin_amdgcn_global_load_lds(
      (const __attribute__((address_space(1))) unsigned int*)g,
      (__attribute__((address_space(3))) unsigned int*)l, 16, 0, 0);
}

// ---------------- Fused quant kernel: blocks [0,4096) = W rows, rest = X.
// W path: per-row ternary absmean quant (exact divides inside rounding).
// X path: per-token per-group(64) absmax fake-quant, 8 elems/thread
//         (group = 8 lanes); pre-round x*scale exact (matches ref), post-round
//         rescale via invs = m/127 multiply (|rel err| ~2^-24, << bf16 2^-8).
__global__ void __launch_bounds__(256) quant_fused_kernel(
    const float* __restrict__ x, unsigned short* __restrict__ xq,
    const float* __restrict__ w, unsigned short* __restrict__ wt,
    float* __restrict__ wscale) {
  const int tid = threadIdx.x;
  if (blockIdx.x < 4096) {
    // ---- W path: one block per row of 4096 ----
    const int row = blockIdx.x;
    const float* wr = w + (long)row * K;
    float4 v[4];
    float s = 0.f;
    #pragma unroll
    for (int p = 0; p < 4; p++) {
      v[p] = ((const float4*)wr)[tid + p * 256];
      s += fabsf(v[p].x) + fabsf(v[p].y) + fabsf(v[p].z) + fabsf(v[p].w);
    }
    #pragma unroll
    for (int d = 1; d < 64; d <<= 1) s += __shfl_xor(s, d);
    __shared__ float red[4];
    if ((tid & 63) == 0) red[tid >> 6] = s;
    __syncthreads();
    const float tot = red[0] + red[1] + red[2] + red[3];
    const float sc = fmaxf(tot / (float)K, EPSf);   // clip(mean|w|, EPS)
    if (tid == 0) wscale[row] = sc;
    unsigned short* wrow = wt + (long)row * K;
    #pragma unroll
    for (int p = 0; p < 4; p++) {
      ushort4 o;
      o.x = f2bf(fminf(fmaxf(rintf(v[p].x / sc), -1.f), 1.f));  // exact in bf16
      o.y = f2bf(fminf(fmaxf(rintf(v[p].y / sc), -1.f), 1.f));
      o.z = f2bf(fminf(fmaxf(rintf(v[p].z / sc), -1.f), 1.f));
      o.w = f2bf(fminf(fmaxf(rintf(v[p].w / sc), -1.f), 1.f));
      ((ushort4*)wrow)[tid + p * 256] = o;
    }
  } else {
    // ---- X path: 8 consecutive elems per thread ----
    const int t = ((int)blockIdx.x - 4096) * 256 + tid;   // 8-elem index
    const float4 v0 = ((const float4*)x)[2 * t];
    const float4 v1 = ((const float4*)x)[2 * t + 1];
    float m = fmaxf(
        fmaxf(fmaxf(fabsf(v0.x), fabsf(v0.y)), fmaxf(fabsf(v0.z), fabsf(v0.w))),
        fmaxf(fmaxf(fabsf(v1.x), fabsf(v1.y)), fmaxf(fabsf(v1.z), fabsf(v1.w))));
    #pragma unroll
    for (int d = 1; d < 8; d <<= 1) m = fmaxf(m, __shfl_xor(m, d));
    m = fmaxf(m, EPSf);                  // clip(absmax, EPS)
    const float scale = QMAX / m;        // exact div: ref's pre-round factor
    const float invs  = m * (1.0f / QMAX);
    const float q[8] = {v0.x, v0.y, v0.z, v0.w, v1.x, v1.y, v1.z, v1.w};
    ushort8 o;
    #pragma unroll
    for (int e = 0; e < 8; e++) {
      const float r = fminf(fmaxf(rintf(q[e] * scale), -QMAX), QMAX);
      o[e] = f2bf(r * invs);
    }
    ((ushort8*)xq)[t] = o;
  }
}

// ---------------- Kernel 3: 256x256-tile 8-phase GEMM (m201 template port)
// C[M,N] = A[M,K] * Bt[N,K]^T, epilogue * wscale[n].
// 8 waves (2M x 4N), per-wave 128x64 output, BK=64, LDS 128 KiB dbuf.
// T1 XCD swizzle + T2 chunk-XOR LDS swizzle + T3/T4 counted vmcnt(6) + T5 setprio.
// NOTE (R2 post-mortem): same-phase ds_read + lgkmcnt(0) coupling is
// load-bearing — decoupling it (1-phase-ahead reg prefetch) let the scheduler
// destroy the phase structure (MfmaUtil 47->33). Do not remove LGKM0.
//
// LDS layout (shorts), per buffer b (b*32768):
//   A half mi: [b*32768 + mi*8192]  rows = (wm*64 + rr), rr = mt*16+r16, 64 k
//   B half nj: [b*32768 + 16384 + nj*8192]  rows = (wn*32 + rr), rr = nt*16+r16
// Swizzle: phys 16B chunk = logical chunk ^ (row&7); applied via pre-swizzled
// global source (linear gload_lds dest) + XOR'd ds_read address (rule #21).
//
// Stage stream runs 7 phases ahead of consumption; per-tile stage order
// {A0,B0,B1,A1}; only vmcnt in main loop = vmcnt(6) at tile boundaries
// (3 half-tiles = 6 wave-loads in flight). vmcnt(0) entering last tile.

#define BAR() do { asm volatile("" ::: "memory"); \
                   __builtin_amdgcn_s_barrier();  \
                   asm volatile("" ::: "memory"); } while (0)
#define LGKM0() asm volatile("s_waitcnt lgkmcnt(0)" ::: "memory")
#define VMCNT(n) asm volatile("s_waitcnt vmcnt(" #n ")" ::: "memory")

__global__ void __launch_bounds__(512, 2) gemm_bt_kernel(const short* __restrict__ A,
                                                         const short* __restrict__ Bt,
                                                         const float* __restrict__ wscale,
                                                         float* __restrict__ C) {
  __shared__ short smem[65536];   // 128 KiB: 2 buffers x (A 16K shorts | B 16K shorts)

  const int tid  = (int)threadIdx.x;
  const int lane = tid & 63;
  const int wv   = tid >> 6;
  const int wm = wv & 1, wn = wv >> 1;        // 2 M-waves x 4 N-waves
  const int quad = lane >> 4, r16 = lane & 15;

  // T1: XCD-aware bijective swizzle (nwg=512, 512 % 8 == 0)
  const int f = (int)blockIdx.x;
  const int s = (f & 7) * 64 + (f >> 3);
  const int m0 = (s >> 4) * 256;              // 32 M-tiles
  const int n0 = (s & 15) * 256;              // 16 N-tiles

  const short* Ab = A  + (long)m0 * K;
  const short* Bb = Bt + (long)n0 * K;

  // Staging constants: thread t, call c stages phys chunk (t&7) of phys row
  // c*64 + (t>>3); logical k-chunk = (t&7) ^ ((t>>3)&7)  (inverse swizzle).
  const int s_row8 = tid >> 3;                              // 0..63
  const int s_kc   = ((tid & 7) ^ (s_row8 & 7)) * 8;        // k elem offset (shorts)

  // ds_read constants: logical chunk kh*4+quad, phys = ^(r16&7); shorts offsets
  const int ksw0 = (((quad * 16)      ) ^ ((r16 & 7) << 4)) >> 1;  // kh=0
  const int ksw1 = (((quad * 16) + 64 ) ^ ((r16 & 7) << 4)) >> 1;  // kh=1
  const int aro  = (wm * 64 + r16) * 64;      // A slot row offset (shorts)
  const int bro  = (wn * 32 + r16) * 64;      // B slot row offset (shorts)

  f32x4 acc[8][4];
  #pragma unroll
  for (int i = 0; i < 8; i++)
    #pragma unroll
    for (int j = 0; j < 4; j++) acc[i][j] = (f32x4){0.f, 0.f, 0.f, 0.f};

  bf16x8 af[4][2];        // current A half fragments (mt, kh)
  bf16x8 bf_[2][2][2];    // both B halves persist     (nj, nt, kh)

#define STAGE_A(buf, hh, kt) do {                                              \
    short* _d = smem + (buf) * 32768 + (hh) * 8192 + tid * 8;                  \
    const short* _g = Ab + (long)((hh) * 64 + s_row8) * K + (kt) * 64 + s_kc;  \
    async_copy16(_g, _d);                                                      \
    async_copy16(_g + (long)128 * K, _d + 4096);                               \
  } while (0)

#define STAGE_B(buf, hh, kt) do {                                              \
    short* _d = smem + (buf) * 32768 + 16384 + (hh) * 8192 + tid * 8;          \
    const int _r0 = (tid >> 8) * 64 + (hh) * 32 + (s_row8 & 31);               \
    const short* _g = Bb + (long)_r0 * K + (kt) * 64 + s_kc;                   \
    async_copy16(_g, _d);                                                      \
    async_copy16(_g + (long)128 * K, _d + 4096);                               \
  } while (0)

#define LOAD_A(buf, mi) do {                                                   \
    const short* _b = smem + (buf) * 32768 + (mi) * 8192 + aro;                \
    _Pragma("unroll") for (int _mt = 0; _mt < 4; ++_mt) {                      \
      af[_mt][0] = *(const bf16x8*)(_b + _mt * 1024 + ksw0);                   \
      af[_mt][1] = *(const bf16x8*)(_b + _mt * 1024 + ksw1);                   \
    }                                                                          \
  } while (0)

#define LOAD_B(buf, nj) do {                                                   \
    const short* _b = smem + (buf) * 32768 + 16384 + (nj) * 8192 + bro;        \
    _Pragma("unroll") for (int _nt = 0; _nt < 2; ++_nt) {                      \
      bf_[nj][_nt][0] = *(const bf16x8*)(_b + _nt * 1024 + ksw0);              \
      bf_[nj][_nt][1] = *(const bf16x8*)(_b + _nt * 1024 + ksw1);              \
    }                                                                          \
  } while (0)

#define MFMA_PHASE(mi, nj) do {                                                \
    BAR(); LGKM0();                                                            \
    __builtin_amdgcn_s_setprio(1);                                             \
    _Pragma("unroll") for (int _mt = 0; _mt < 4; ++_mt)                        \
    _Pragma("unroll") for (int _nt = 0; _nt < 2; ++_nt) {                      \
      acc[(mi)*4+_mt][(nj)*2+_nt] = __builtin_amdgcn_mfma_f32_16x16x32_bf16(   \
          af[_mt][0], bf_[nj][_nt][0], acc[(mi)*4+_mt][(nj)*2+_nt], 0, 0, 0);  \
      acc[(mi)*4+_mt][(nj)*2+_nt] = __builtin_amdgcn_mfma_f32_16x16x32_bf16(   \
          af[_mt][1], bf_[nj][_nt][1], acc[(mi)*4+_mt][(nj)*2+_nt], 0, 0, 0);  \
    }                                                                          \
    __builtin_amdgcn_s_setprio(0);                                             \
  } while (0)

  // Prologue: stage half-tiles #0..6 (tile0 full + tile1 A0,B0,B1)
  STAGE_A(0, 0, 0); STAGE_B(0, 0, 0); STAGE_B(0, 1, 0); STAGE_A(0, 1, 0);
  VMCNT(4);
  STAGE_A(1, 0, 1); STAGE_B(1, 0, 1); STAGE_B(1, 1, 1);
  VMCNT(6);          // tile 0 fully resident; tile1 partials in flight
  BAR();

  for (int kt = 0; kt < 64; kt += 2) {
    const bool g2 = (kt + 2) < 64;
    const bool g3 = (kt + 3) < 64;

    // ======== tile kt (buf 0) ========
    // ph1: quadrant (mi0,nj0); stage tile kt+1 A1 -> buf1
    LOAD_A(0, 0); LOAD_B(0, 0);
    STAGE_A(1, 1, kt + 1);
    MFMA_PHASE(0, 0); BAR();
    // ph2: (mi0,nj1); stage tile kt+2 A0 -> buf0 (A0 read done in ph1)
    LOAD_B(0, 1);
    if (g2) STAGE_A(0, 0, kt + 2);
    MFMA_PHASE(0, 1); BAR();
    // ph3: (mi1,nj1); stage tile kt+2 B0 (B0 cached in regs since ph1)
    LOAD_A(0, 1);
    if (g2) STAGE_B(0, 0, kt + 2);
    MFMA_PHASE(1, 1); BAR();
    // ph4: (mi1,nj0) from cached regs; stage tile kt+2 B1; tile boundary
    if (g2) STAGE_B(0, 1, kt + 2);
    MFMA_PHASE(1, 0);
    if (kt == 62) { VMCNT(0); } else { VMCNT(6); }   // next tile fully staged
    BAR();

    // ======== tile kt+1 (buf 1) ========
    // ph5: (mi0,nj0); stage tile kt+2 A1 -> buf0
    LOAD_A(1, 0); LOAD_B(1, 0);
    if (g2) STAGE_A(0, 1, kt + 2);
    MFMA_PHASE(0, 0); BAR();
    // ph6: (mi0,nj1); stage tile kt+3 A0 -> buf1
    LOAD_B(1, 1);
    if (g3) STAGE_A(1, 0, kt + 3);
    MFMA_PHASE(0, 1); BAR();
    // ph7: (mi1,nj1); stage tile kt+3 B0
    LOAD_A(1, 1);
    if (g3) STAGE_B(1, 0, kt + 3);
    MFMA_PHASE(1, 1); BAR();
    // ph8: (mi1,nj0); stage tile kt+3 B1; tile boundary
    if (g3) STAGE_B(1, 1, kt + 3);
    MFMA_PHASE(1, 0);
    if (g2) { VMCNT(6); BAR(); }    // else: last tile done, fall out
  }

  // Epilogue: D[row = quad*4+r][col = r16] per 16x16 frag; scale by wscale[col]
  #pragma unroll
  for (int an = 0; an < 4; ++an) {
    const int col = n0 + wn * 64 + (an >> 1) * 32 + (an & 1) * 16 + r16;
    const float sc = wscale[col];
    #pragma unroll
    for (int am = 0; am < 8; ++am) {
      const int rb = m0 + wm * 128 + (am >> 2) * 64 + (am & 3) * 16 + quad * 4;
      #pragma unroll
      for (int r = 0; r < 4; ++r)
        C[(long)(rb + r) * N + col] = acc[am][an][r] * sc;
    }
  }
}

extern "C" void kernel_launch(void* const* d_in, const int* in_sizes, int n_in,
                              void* d_out, int out_size, void* d_ws, size_t ws_size,
                              hipStream_t stream) {
  const float* x   = (const float*)d_in[0];   // [4,2048,4096] fp32
  const float* wgt = (const float*)d_in[1];   // [4096,4096] fp32
  float* out = (float*)d_out;                 // [4,2048,4096] fp32

  // Workspace layout: A bf16 [M*K] | T bf16 [N*K] | wscale f32 [N]  (~96 MB)
  unsigned short* Aq = (unsigned short*)d_ws;
  unsigned short* Tq = Aq + (size_t)M * K;
  float* wscale = (float*)(Tq + (size_t)N * K);

  // One fused quant dispatch: blocks [0,4096) quantize W rows, blocks
  // [4096, 4096+16384) quantize X (8 elems/thread).
  quant_fused_kernel<<<4096 + (M * K / 8) / 256, 256, 0, stream>>>(
      x, Aq, wgt, Tq, wscale);

  gemm_bt_kernel<<<dim3(512), dim3(512), 0, stream>>>((const short*)Aq, (const short*)Tq,
                                                      wscale, out);
}